// Round 11
// baseline (200.771 us; speedup 1.0000x reference)
//
#include <hip/hip_runtime.h>
#include <hip/hip_bf16.h>

#define NJ 24
#define NV 6890
#define NR (NV*3)        // 20670 output rows per batch
#define NPF 207
#define KB 217           // 207 pf + 10 beta
#define KP 256           // padded K (8 x 32)
#define NT 162           // n-tiles (162*128 = 20736 >= NR)
#define NSPLIT 512       // jdirs v-splits
#define VPB 14           // ceil(6890/512)
#define FTILE 32768      // shorts per fragment tile: 8 ks * 8 frag * 64 lane * 8

typedef short s16x8 __attribute__((ext_vector_type(8)));
typedef float f32x4 __attribute__((ext_vector_type(4)));
typedef float f4u   __attribute__((ext_vector_type(4), aligned(4)));

__device__ constexpr int PAR[24] = {-1,0,0,0,1,2,3,4,5,6,7,8,9,9,9,12,13,14,16,17,18,19,20,21};

__device__ __forceinline__ short f2bf(float f) {
    __hip_bfloat16 h = __float2bfloat16(f);
    return *reinterpret_cast<short*>(&h);
}

// fragment address for matrix element (row_in_tile, k)
__device__ __forceinline__ size_t frag_addr(int row128, int k) {
    int ks = k >> 5, q = (k >> 3) & 3, e = k & 7;
    int mf = row128 >> 4, r16 = row128 & 15;
    return ((size_t)(ks*8 + mf) * 64 + q*16 + r16) * 8 + e;
}

// ============ K1: Rodrigues -> Rws(f32), pfA(f32), Afrag(bf16 fragment layout) ============
__global__ __launch_bounds__(256) void k_rodrigues(const float* __restrict__ theta,
        const float* __restrict__ beta, float* __restrict__ Rws,
        float* __restrict__ pfA, short* __restrict__ Afrag, int B) {
    int idx = blockIdx.x * blockDim.x + threadIdx.x;   // b*24 + j
    if (idx >= B * NJ) return;
    int b = idx / NJ, j = idx % NJ;
    float x = theta[b*72 + j*3 + 0];
    float y = theta[b*72 + j*3 + 1];
    float z = theta[b*72 + j*3 + 2];
    float n = sqrtf(x*x + y*y + z*z);
    float a = fmaxf(n, 1e-8f);
    float inv = 1.0f / a;
    float ix = x*inv, iy = y*inv, iz = z*inv;
    float c = cosf(a), s = sinf(a), t = 1.0f - c;
    float r[9];
    r[0] = t*ix*ix + c;     r[1] = t*ix*iy - s*iz;  r[2] = t*ix*iz + s*iy;
    r[3] = t*ix*iy + s*iz;  r[4] = t*iy*iy + c;     r[5] = t*iy*iz - s*ix;
    r[6] = t*ix*iz - s*iy;  r[7] = t*iy*iz + s*ix;  r[8] = t*iz*iz + c;
    float* Rp = Rws + (size_t)idx * 9;
    #pragma unroll
    for (int k = 0; k < 9; ++k) Rp[k] = r[k];

    int rb = b & 127;
    short* At = Afrag + (size_t)(b >> 7) * FTILE;
    float* pa = pfA + (size_t)b * 224;
    if (j >= 1) {
        #pragma unroll
        for (int kk = 0; kk < 9; ++kk) {
            int k = (j-1)*9 + kk;
            float f = r[kk] - ((kk == 0 || kk == 4 || kk == 8) ? 1.0f : 0.0f);
            At[frag_addr(rb, k)] = f2bf(f);
            pa[k] = f;
        }
    } else {
        #pragma unroll
        for (int kk = 0; kk < 10; ++kk) {
            int k = NPF + kk;
            float f = beta[b*10 + kk];
            At[frag_addr(rb, k)] = f2bf(f);
            pa[k] = f;
        }
        for (int k = KB; k < KP; ++k)
            At[frag_addr(rb, k)] = 0;
    }
}

// ============ K2: build Bfrag (bf16, fragment layout, coalesced writes) ============
__global__ __launch_bounds__(256) void k_convB(const float* __restrict__ pd,
        const float* __restrict__ sd, short* __restrict__ Bf) {
    int cid = blockIdx.x * 256 + threadIdx.x;      // chunk id: [nt][ks][nf][lane]
    int lane_ = cid & 63;
    int nf = (cid >> 6) & 7;
    int ks = (cid >> 9) & 7;
    int nt = cid >> 12;
    int q = lane_ >> 4, r16 = lane_ & 15;
    int rg = nt*128 + nf*16 + r16;
    int k0 = ks*32 + q*8;
    s16x8 v;
    if (rg < NR) {
        if (k0 + 7 < NPF) {
            const float* p = pd + (size_t)rg * NPF + k0;
            #pragma unroll
            for (int k = 0; k < 8; ++k) v[k] = f2bf(p[k]);
        } else {
            #pragma unroll
            for (int k = 0; k < 8; ++k) {
                int col = k0 + k;
                float f = 0.0f;
                if (col < NPF)     f = pd[(size_t)rg * NPF + col];
                else if (col < KB) f = sd[(size_t)rg * 10 + (col - NPF)];
                v[k] = f2bf(f);
            }
        }
    } else {
        #pragma unroll
        for (int k = 0; k < 8; ++k) v[k] = 0;
    }
    *(s16x8*)&Bf[(size_t)cid * 8] = v;
}

// ============ K3: JD partials, part layout [bi][i(72)][k(224)] ============
__global__ __launch_bounds__(256) void k_jdirs(const float* __restrict__ pd,
        const float* __restrict__ sd, const float* __restrict__ vt,
        const float* __restrict__ Jreg, float* __restrict__ part) {
    __shared__ float wjs[24][VPB];
    int bi = blockIdx.x;
    int v0 = bi * VPB;
    int nv = NV - v0; if (nv > VPB) nv = VPB; if (nv < 0) nv = 0;
    for (int i = threadIdx.x; i < 24*VPB; i += 256) {
        int j = i / VPB, vv = i - j*VPB;
        wjs[j][vv] = (vv < nv) ? Jreg[(size_t)j * NV + v0 + vv] : 0.0f;
    }
    __syncthreads();
    int k = threadIdx.x;
    float acc[72];
    #pragma unroll
    for (int i = 0; i < 72; ++i) acc[i] = 0.0f;
    for (int vv = 0; vv < VPB; ++vv) {
        int v = v0 + vv;
        if (v >= NV) break;
        #pragma unroll
        for (int c = 0; c < 3; ++c) {
            int row = v*3 + c;
            float val = 0.0f;
            if (k < NPF)      val = pd[(size_t)row * NPF + k];
            else if (k < KB)  val = sd[(size_t)row * 10 + (k - NPF)];
            else if (k == KB) val = vt[row];
            #pragma unroll
            for (int j = 0; j < 24; ++j) acc[j*3 + c] += wjs[j][vv] * val;
        }
    }
    if (k < 224) {
        float* p = part + (size_t)bi * (72*224);
        #pragma unroll
        for (int i = 0; i < 72; ++i) p[i*224 + k] = acc[i];
    }
}

// ============ K4a: reduce 512 -> 8 partials, coalesced ============
__global__ __launch_bounds__(256) void k_jreduce1(const float* __restrict__ part,
        float* __restrict__ part2) {
    int i = blockIdx.x;            // 0..71
    int s = blockIdx.y;            // 0..7
    int k = threadIdx.x;
    if (k >= 224) return;
    float acc = 0.0f;
    #pragma unroll 4
    for (int bi = s*64; bi < s*64 + 64; ++bi)
        acc += part[(size_t)bi * (72*224) + i*224 + k];
    part2[((size_t)s * 72 + i) * 224 + k] = acc;
}

// ============ K4b: reduce 8 -> JDt[k][72] ============
__global__ __launch_bounds__(256) void k_jreduce2(const float* __restrict__ part2,
        float* __restrict__ JDt) {
    int e = blockIdx.x * 256 + threadIdx.x;    // e = i*224 + k
    if (e >= 72*224) return;
    int i = e / 224, k = e - i*224;
    float s = 0.0f;
    #pragma unroll
    for (int ss = 0; ss < 8; ++ss)
        s += part2[((size_t)ss * 72 + i) * 224 + k];
    if (k < 218) JDt[k*72 + i] = s;
}

// ============ K5: merged J + kinematic chain (32 batches/block) ============
// phase 1: J[b][jc] = JDt[217][jc] + pfA[b][:].JDt[:][jc]  -> LDS + Jout
// phase 2: chain per batch (threads 0..31) -> G_corr
__global__ __launch_bounds__(256) void k_chainJ(const float* __restrict__ pfA,
        const float* __restrict__ JDt, const float* __restrict__ Rg,
        float* __restrict__ Jout, float* __restrict__ Gc, int B) {
    __shared__ float Jl[32][72];
    __shared__ float Gs[32 * 289];
    int b0 = blockIdx.x * 32;
    int t = threadIdx.x;

    // phase 1: 32*72 = 2304 outputs, 9 per thread
    #pragma unroll
    for (int o = 0; o < 9; ++o) {
        int e = o * 256 + t;                   // e = bb*72 + jc
        int bb = e / 72, jc = e - bb * 72;
        int b = b0 + bb;
        if (b < B) {
            const float* pa = pfA + (size_t)b * 224;
            float acc = JDt[217*72 + jc];
            #pragma unroll 7
            for (int k = 0; k < KB; ++k) acc += pa[k] * JDt[k*72 + jc];
            Jl[bb][jc] = acc;
            Jout[(size_t)b * 72 + jc] = acc;
        }
    }
    __syncthreads();

    // phase 2: chain, one thread per batch
    if (t >= 32) return;
    int b = b0 + t;
    if (b >= B) return;
    float* G = &Gs[t * 289];
    float Jb[72];
    #pragma unroll
    for (int i = 0; i < 72; ++i) Jb[i] = Jl[t][i];
    const float* Rb = Rg + (size_t)b * 216;
    G[0]=Rb[0]; G[1]=Rb[1]; G[2]=Rb[2];  G[3]=Jb[0];
    G[4]=Rb[3]; G[5]=Rb[4]; G[6]=Rb[5];  G[7]=Jb[1];
    G[8]=Rb[6]; G[9]=Rb[7]; G[10]=Rb[8]; G[11]=Jb[2];
    #pragma unroll
    for (int i = 1; i < NJ; ++i) {
        const int p = PAR[i];
        const float* Ri = Rb + i*9;
        float r00=Ri[0],r01=Ri[1],r02=Ri[2];
        float r10=Ri[3],r11=Ri[4],r12=Ri[5];
        float r20=Ri[6],r21=Ri[7],r22=Ri[8];
        float px=Jb[p*3+0], py=Jb[p*3+1], pz=Jb[p*3+2];
        float tx = Jb[i*3+0] - (r00*px + r01*py + r02*pz);
        float ty = Jb[i*3+1] - (r10*px + r11*py + r12*pz);
        float tz = Jb[i*3+2] - (r20*px + r21*py + r22*pz);
        const float* gp = &G[p*12];
        float* gi = &G[i*12];
        #pragma unroll
        for (int rr = 0; rr < 3; ++rr) {
            float a0=gp[rr*4+0], a1=gp[rr*4+1], a2=gp[rr*4+2], a3=gp[rr*4+3];
            gi[rr*4+0] = a0*r00 + a1*r10 + a2*r20;
            gi[rr*4+1] = a0*r01 + a1*r11 + a2*r21;
            gi[rr*4+2] = a0*r02 + a1*r12 + a2*r22;
            gi[rr*4+3] = a0*tx + a1*ty + a2*tz + a3;
        }
    }
    float* outp = Gc + (size_t)b * 288;
    #pragma unroll
    for (int i = 0; i < NJ; ++i) {
        const float* gi = &G[i*12];
        float jx=Jb[i*3+0], jy=Jb[i*3+1], jz=Jb[i*3+2];
        #pragma unroll
        for (int rr = 0; rr < 3; ++rr) {
            outp[i*12+rr*4+0] = gi[rr*4+0];
            outp[i*12+rr*4+1] = gi[rr*4+1];
            outp[i*12+rr*4+2] = gi[rr*4+2];
            outp[i*12+rr*4+3] = gi[rr*4+3] - (gi[rr*4+0]*jx + gi[rr*4+1]*jy + gi[rr*4+2]*jz);
        }
    }
}

// ============ K6: streaming-fragment MFMA GEMM (exact R8 config, 51 us proven) ============
__global__ __launch_bounds__(256, 2) void k_gemm(const short* __restrict__ Af,
        const short* __restrict__ Bf, const float* __restrict__ vt,
        float* __restrict__ vout, int B) {
    __shared__ float eld[64 * 128];                // 32 KB, epilogue transpose only
    const int t = threadIdx.x;
    const int wgid = blockIdx.x;
    const int bt = wgid & 7, nt = wgid >> 3;       // bt per XCD (round-robin dispatch)
    const int wave = t >> 6, lane = t & 63;
    const int wn = (wave & 1) * 64;
    const int q = lane >> 4, r16 = lane & 15;
    const int mfb = (wave >> 1) * 4, nfb = (wave & 1) * 4;

    const s16x8* Ab = (const s16x8*)(Af + (size_t)bt * FTILE);
    const s16x8* Bb = (const s16x8*)(Bf + (size_t)nt * FTILE);

    f32x4 acc[4][4];
    #pragma unroll
    for (int m = 0; m < 4; ++m)
        #pragma unroll
        for (int n = 0; n < 4; ++n)
            #pragma unroll
            for (int i = 0; i < 4; ++i) acc[m][n][i] = 0.0f;

    #pragma unroll
    for (int ks = 0; ks < 8; ++ks) {
        s16x8 a[4], b[4];
        #pragma unroll
        for (int m = 0; m < 4; ++m) a[m] = Ab[(ks*8 + mfb + m)*64 + lane];
        #pragma unroll
        for (int n = 0; n < 4; ++n) b[n] = Bb[(ks*8 + nfb + n)*64 + lane];
        #pragma unroll
        for (int m = 0; m < 4; ++m)
            #pragma unroll
            for (int n = 0; n < 4; ++n)
                acc[m][n] = __builtin_amdgcn_mfma_f32_16x16x32_bf16(a[m], b[n], acc[m][n], 0, 0, 0);
    }

    // ---- epilogue: two 64-row halves through LDS, 512B-contiguous row stores ----
    #pragma unroll
    for (int half = 0; half < 2; ++half) {
        if ((wave >> 1) == half) {
            #pragma unroll
            for (int m = 0; m < 4; ++m) {
                #pragma unroll
                for (int n = 0; n < 4; ++n) {
                    #pragma unroll
                    for (int i = 0; i < 4; ++i) {
                        int row_l = m*16 + q*4 + i;              // 0..63
                        int col = wn + n*16 + r16;               // 0..127
                        eld[row_l * 128 + (col ^ ((row_l & 7) << 2))] = acc[m][n][i];
                    }
                }
            }
        }
        __syncthreads();
        {
            const int c32 = t & 31;
            const int col = c32 * 4;
            const int rsub = (t >> 5) & 1;
            #pragma unroll
            for (int it = 0; it < 8; ++it) {
                int row_l = it * 8 + wave * 2 + rsub;            // 0..63
                int bg = bt * 128 + half * 64 + row_l;
                int rg = nt * 128 + col;
                f32x4 v = *(const f32x4*)&eld[row_l * 128 + (col ^ ((row_l & 7) << 2))];
                if (bg < B) {
                    float* dst = vout + (size_t)bg * NR + rg;
                    if (rg + 3 < NR) {
                        float4 tv = *(const float4*)(vt + rg);
                        v[0] += tv.x; v[1] += tv.y; v[2] += tv.z; v[3] += tv.w;
                        *(f4u*)dst = v;
                    } else {
                        #pragma unroll
                        for (int e = 0; e < 4; ++e)
                            if (rg + e < NR) dst[e] = v[e] + vt[rg + e];
                    }
                }
            }
        }
        __syncthreads();
    }
}

// ============ K8: MFMA skinning (R4-proven), 16 batches/block ============
__global__ __launch_bounds__(256) void k_skin(float* __restrict__ vio,
        const float* __restrict__ W, const float* __restrict__ Gc, int B) {
    __shared__ short Gm[16 * 40];
    const int t = threadIdx.x;
    const int wave = t >> 6, lane = t & 63;
    const int q = lane >> 4, c = lane & 15;
    const int vb = blockIdx.x * 256 + wave * 64;
    const int b0 = blockIdx.y * 16;

    if (t < 320) ((int*)Gm)[t] = 0;

    s16x8 wf[4];
    #pragma unroll
    for (int m = 0; m < 4; ++m) {
        int vert = vb + m*16 + c;
        if (q < 3 && vert < NV) {
            const float* wp = W + (size_t)vert * NJ + q*8;
            float4 f0 = *(const float4*)(wp);
            float4 f1 = *(const float4*)(wp + 4);
            wf[m][0]=f2bf(f0.x); wf[m][1]=f2bf(f0.y); wf[m][2]=f2bf(f0.z); wf[m][3]=f2bf(f0.w);
            wf[m][4]=f2bf(f1.x); wf[m][5]=f2bf(f1.y); wf[m][6]=f2bf(f1.z); wf[m][7]=f2bf(f1.w);
        } else {
            #pragma unroll
            for (int e = 0; e < 8; ++e) wf[m][e] = 0;
        }
    }
    __syncthreads();

    for (int bb = 0; bb < 16; ++bb) {
        int b = b0 + bb;
        if (b >= B) break;
        {
            int i0 = t;
            int j0 = i0 / 12, c0 = i0 - j0*12;
            if (i0 < 288) Gm[c0*40 + j0] = f2bf(Gc[(size_t)b*288 + i0]);
            int i1 = t + 256;
            if (i1 < 288) {
                int j1 = i1 / 12, c1 = i1 - j1*12;
                Gm[c1*40 + j1] = f2bf(Gc[(size_t)b*288 + i1]);
            }
        }
        __syncthreads();

        s16x8 af = *(const s16x8*)&Gm[c*40 + q*8];
        #pragma unroll
        for (int m = 0; m < 4; ++m) {
            f32x4 zz = {0.0f, 0.0f, 0.0f, 0.0f};
            f32x4 acc = __builtin_amdgcn_mfma_f32_16x16x32_bf16(af, wf[m], zz, 0, 0, 0);
            int vert = vb + m*16 + c;
            bool ok = (q < 3) && (vert < NV);
            if (ok) {
                float* vp = vio + (size_t)b * NR + (size_t)vert * 3;
                float x = vp[0], y = vp[1], z = vp[2];
                float o = acc[0]*x + acc[1]*y + acc[2]*z + acc[3];
                vp[q] = o;
            }
        }
        __syncthreads();
    }
}

extern "C" void kernel_launch(void* const* d_in, const int* in_sizes, int n_in,
                              void* d_out, int out_size, void* d_ws, size_t ws_size,
                              hipStream_t stream) {
    const float* theta = (const float*)d_in[0];
    const float* beta  = (const float*)d_in[1];
    const float* sd    = (const float*)d_in[2];
    const float* pd    = (const float*)d_in[3];
    const float* Jreg  = (const float*)d_in[4];
    const float* vt    = (const float*)d_in[5];
    const float* W     = (const float*)d_in[6];
    float* out = (float*)d_out;

    const int B = in_sizes[0] / 72;

    float* vregion = out;
    float* Jout    = out + (size_t)B * NR;

    float* Rws   = (float*)d_ws;                          // B*216 f32
    float* Gcws  = Rws + (size_t)B * 216;                 // B*288 f32
    float* pfA   = Gcws + (size_t)B * 288;                // B*224 f32
    short* Afrag = (short*)(pfA + (size_t)B * 224);       // 8*FTILE bf16 (512 KB)
    short* Bfrag = Afrag + (size_t)(B/128) * FTILE;       // 162*FTILE bf16 (10.4 MB)

    float* part  = vregion;                               // d_out scratch pre-GEMM
    float* part2 = vregion + (size_t)NSPLIT * 72 * 224;
    float* JDt   = part2 + (size_t)8 * 72 * 224;

    k_rodrigues<<<(B*NJ + 255)/256, 256, 0, stream>>>(theta, beta, Rws, pfA, Afrag, B);
    k_convB<<<(NT*8*8*64)/256, 256, 0, stream>>>(pd, sd, Bfrag);
    k_jdirs<<<NSPLIT, 256, 0, stream>>>(pd, sd, vt, Jreg, part);
    {
        dim3 grid(72, 8);
        k_jreduce1<<<grid, 256, 0, stream>>>(part, part2);
    }
    k_jreduce2<<<(72*224 + 255)/256, 256, 0, stream>>>(part2, JDt);
    k_chainJ<<<(B + 31)/32, 256, 0, stream>>>(pfA, JDt, Rws, Jout, Gcws, B);
    // streaming-fragment GEMM: 1-D grid, bt = wgid & 7 keeps one A-tile per XCD
    k_gemm<<<NT * (B/128), 256, 0, stream>>>(Afrag, Bfrag, vt, vregion, B);
    {
        dim3 grid((NV + 255)/256, (B + 15)/16);
        k_skin<<<grid, 256, 0, stream>>>(vregion, W, Gcws, B);
    }
}

// Round 12
// 154.401 us; speedup vs baseline: 1.3003x; 1.3003x over previous
//
#include <hip/hip_runtime.h>
#include <hip/hip_bf16.h>

#define NJ 24
#define NV 6890
#define NR (NV*3)        // 20670 output rows per batch
#define NPF 207
#define KB 217           // 207 pf + 10 beta
#define KP 256           // padded K (8 x 32)
#define NT 162           // n-tiles (162*128 = 20736 >= NR)
#define NSPLIT 512       // jdirs v-splits
#define VPB 14           // ceil(6890/512)
#define FTILE 32768      // shorts per fragment tile: 8 ks * 8 frag * 64 lane * 8

typedef short s16x8 __attribute__((ext_vector_type(8)));
typedef float f32x4 __attribute__((ext_vector_type(4)));
typedef float f4u   __attribute__((ext_vector_type(4), aligned(4)));

__device__ constexpr int PAR[24] = {-1,0,0,0,1,2,3,4,5,6,7,8,9,9,9,12,13,14,16,17,18,19,20,21};

__device__ __forceinline__ short f2bf(float f) {
    __hip_bfloat16 h = __float2bfloat16(f);
    return *reinterpret_cast<short*>(&h);
}

// fragment address for matrix element (row_in_tile, k)
__device__ __forceinline__ size_t frag_addr(int row128, int k) {
    int ks = k >> 5, q = (k >> 3) & 3, e = k & 7;
    int mf = row128 >> 4, r16 = row128 & 15;
    return ((size_t)(ks*8 + mf) * 64 + q*16 + r16) * 8 + e;
}

// ============ K1: Rodrigues -> Rws(f32), pfA(f32), Afrag(bf16 fragment layout) ============
__global__ __launch_bounds__(256) void k_rodrigues(const float* __restrict__ theta,
        const float* __restrict__ beta, float* __restrict__ Rws,
        float* __restrict__ pfA, short* __restrict__ Afrag, int B) {
    int idx = blockIdx.x * blockDim.x + threadIdx.x;   // b*24 + j
    if (idx >= B * NJ) return;
    int b = idx / NJ, j = idx % NJ;
    float x = theta[b*72 + j*3 + 0];
    float y = theta[b*72 + j*3 + 1];
    float z = theta[b*72 + j*3 + 2];
    float n = sqrtf(x*x + y*y + z*z);
    float a = fmaxf(n, 1e-8f);
    float inv = 1.0f / a;
    float ix = x*inv, iy = y*inv, iz = z*inv;
    float c = cosf(a), s = sinf(a), t = 1.0f - c;
    float r[9];
    r[0] = t*ix*ix + c;     r[1] = t*ix*iy - s*iz;  r[2] = t*ix*iz + s*iy;
    r[3] = t*ix*iy + s*iz;  r[4] = t*iy*iy + c;     r[5] = t*iy*iz - s*ix;
    r[6] = t*ix*iz - s*iy;  r[7] = t*iy*iz + s*ix;  r[8] = t*iz*iz + c;
    float* Rp = Rws + (size_t)idx * 9;
    #pragma unroll
    for (int k = 0; k < 9; ++k) Rp[k] = r[k];

    int rb = b & 127;
    short* At = Afrag + (size_t)(b >> 7) * FTILE;
    float* pa = pfA + (size_t)b * 224;
    if (j >= 1) {
        #pragma unroll
        for (int kk = 0; kk < 9; ++kk) {
            int k = (j-1)*9 + kk;
            float f = r[kk] - ((kk == 0 || kk == 4 || kk == 8) ? 1.0f : 0.0f);
            At[frag_addr(rb, k)] = f2bf(f);
            pa[k] = f;
        }
    } else {
        #pragma unroll
        for (int kk = 0; kk < 10; ++kk) {
            int k = NPF + kk;
            float f = beta[b*10 + kk];
            At[frag_addr(rb, k)] = f2bf(f);
            pa[k] = f;
        }
        for (int k = KB; k < KP; ++k)
            At[frag_addr(rb, k)] = 0;
    }
}

// ============ K2: build Bfrag (bf16, fragment layout, coalesced writes) ============
__global__ __launch_bounds__(256) void k_convB(const float* __restrict__ pd,
        const float* __restrict__ sd, short* __restrict__ Bf) {
    int cid = blockIdx.x * 256 + threadIdx.x;      // chunk id: [nt][ks][nf][lane]
    int lane_ = cid & 63;
    int nf = (cid >> 6) & 7;
    int ks = (cid >> 9) & 7;
    int nt = cid >> 12;
    int q = lane_ >> 4, r16 = lane_ & 15;
    int rg = nt*128 + nf*16 + r16;
    int k0 = ks*32 + q*8;
    s16x8 v;
    if (rg < NR) {
        if (k0 + 7 < NPF) {
            const float* p = pd + (size_t)rg * NPF + k0;
            #pragma unroll
            for (int k = 0; k < 8; ++k) v[k] = f2bf(p[k]);
        } else {
            #pragma unroll
            for (int k = 0; k < 8; ++k) {
                int col = k0 + k;
                float f = 0.0f;
                if (col < NPF)     f = pd[(size_t)rg * NPF + col];
                else if (col < KB) f = sd[(size_t)rg * 10 + (col - NPF)];
                v[k] = f2bf(f);
            }
        }
    } else {
        #pragma unroll
        for (int k = 0; k < 8; ++k) v[k] = 0;
    }
    *(s16x8*)&Bf[(size_t)cid * 8] = v;
}

// ============ K3: JD partials, part layout [bi][i(72)][k(224)] ============
__global__ __launch_bounds__(256) void k_jdirs(const float* __restrict__ pd,
        const float* __restrict__ sd, const float* __restrict__ vt,
        const float* __restrict__ Jreg, float* __restrict__ part) {
    __shared__ float wjs[24][VPB];
    int bi = blockIdx.x;
    int v0 = bi * VPB;
    int nv = NV - v0; if (nv > VPB) nv = VPB; if (nv < 0) nv = 0;
    for (int i = threadIdx.x; i < 24*VPB; i += 256) {
        int j = i / VPB, vv = i - j*VPB;
        wjs[j][vv] = (vv < nv) ? Jreg[(size_t)j * NV + v0 + vv] : 0.0f;
    }
    __syncthreads();
    int k = threadIdx.x;
    float acc[72];
    #pragma unroll
    for (int i = 0; i < 72; ++i) acc[i] = 0.0f;
    for (int vv = 0; vv < VPB; ++vv) {
        int v = v0 + vv;
        if (v >= NV) break;
        #pragma unroll
        for (int c = 0; c < 3; ++c) {
            int row = v*3 + c;
            float val = 0.0f;
            if (k < NPF)      val = pd[(size_t)row * NPF + k];
            else if (k < KB)  val = sd[(size_t)row * 10 + (k - NPF)];
            else if (k == KB) val = vt[row];
            #pragma unroll
            for (int j = 0; j < 24; ++j) acc[j*3 + c] += wjs[j][vv] * val;
        }
    }
    if (k < 224) {
        float* p = part + (size_t)bi * (72*224);
        #pragma unroll
        for (int i = 0; i < 72; ++i) p[i*224 + k] = acc[i];
    }
}

// ============ K4a: reduce 512 -> 8 partials, coalesced ============
__global__ __launch_bounds__(256) void k_jreduce1(const float* __restrict__ part,
        float* __restrict__ part2) {
    int i = blockIdx.x;            // 0..71
    int s = blockIdx.y;            // 0..7
    int k = threadIdx.x;
    if (k >= 224) return;
    float acc = 0.0f;
    #pragma unroll 4
    for (int bi = s*64; bi < s*64 + 64; ++bi)
        acc += part[(size_t)bi * (72*224) + i*224 + k];
    part2[((size_t)s * 72 + i) * 224 + k] = acc;
}

// ============ K4b: reduce 8 -> JDt[k][72] ============
__global__ __launch_bounds__(256) void k_jreduce2(const float* __restrict__ part2,
        float* __restrict__ JDt) {
    int e = blockIdx.x * 256 + threadIdx.x;    // e = i*224 + k
    if (e >= 72*224) return;
    int i = e / 224, k = e - i*224;
    float s = 0.0f;
    #pragma unroll
    for (int ss = 0; ss < 8; ++ss)
        s += part2[((size_t)ss * 72 + i) * 224 + k];
    if (k < 218) JDt[k*72 + i] = s;
}

// ============ K5: J[b][jc] = JDt[217][jc] + sum_k pfA[b][k]*JDt[k][jc] ============
__global__ __launch_bounds__(128) void k_J(const float* __restrict__ pfA,
        const float* __restrict__ JDt, float* __restrict__ Jout, int B) {
    int b = blockIdx.x, t = threadIdx.x;
    if (t >= 72) return;
    const float* pa = pfA + (size_t)b * 224;
    float acc = JDt[217*72 + t];
    #pragma unroll 7
    for (int k = 0; k < KB; ++k) acc += pa[k] * JDt[k*72 + t];
    Jout[(size_t)b * 72 + t] = acc;
}

// ============ K6: kinematic chain -> G_corr (B,24,12) ============
__global__ __launch_bounds__(32) void k_chain(const float* __restrict__ Rg,
        const float* __restrict__ Jg, float* __restrict__ Gc, int B) {
    __shared__ float Gs[32 * 289];
    int b = blockIdx.x * 32 + threadIdx.x;
    if (b >= B) return;
    float* G = &Gs[threadIdx.x * 289];
    float Jl[72];
    const float* Jb = Jg + (size_t)b * 72;
    #pragma unroll
    for (int i = 0; i < 72; ++i) Jl[i] = Jb[i];
    const float* Rb = Rg + (size_t)b * 216;
    G[0]=Rb[0]; G[1]=Rb[1]; G[2]=Rb[2];  G[3]=Jl[0];
    G[4]=Rb[3]; G[5]=Rb[4]; G[6]=Rb[5];  G[7]=Jl[1];
    G[8]=Rb[6]; G[9]=Rb[7]; G[10]=Rb[8]; G[11]=Jl[2];
    #pragma unroll
    for (int i = 1; i < NJ; ++i) {
        const int p = PAR[i];
        const float* Ri = Rb + i*9;
        float r00=Ri[0],r01=Ri[1],r02=Ri[2];
        float r10=Ri[3],r11=Ri[4],r12=Ri[5];
        float r20=Ri[6],r21=Ri[7],r22=Ri[8];
        float px=Jl[p*3+0], py=Jl[p*3+1], pz=Jl[p*3+2];
        float tx = Jl[i*3+0] - (r00*px + r01*py + r02*pz);
        float ty = Jl[i*3+1] - (r10*px + r11*py + r12*pz);
        float tz = Jl[i*3+2] - (r20*px + r21*py + r22*pz);
        const float* gp = &G[p*12];
        float* gi = &G[i*12];
        #pragma unroll
        for (int rr = 0; rr < 3; ++rr) {
            float a0=gp[rr*4+0], a1=gp[rr*4+1], a2=gp[rr*4+2], a3=gp[rr*4+3];
            gi[rr*4+0] = a0*r00 + a1*r10 + a2*r20;
            gi[rr*4+1] = a0*r01 + a1*r11 + a2*r21;
            gi[rr*4+2] = a0*r02 + a1*r12 + a2*r22;
            gi[rr*4+3] = a0*tx + a1*ty + a2*tz + a3;
        }
    }
    float* out = Gc + (size_t)b * 288;
    #pragma unroll
    for (int i = 0; i < NJ; ++i) {
        const float* gi = &G[i*12];
        float jx=Jl[i*3+0], jy=Jl[i*3+1], jz=Jl[i*3+2];
        #pragma unroll
        for (int rr = 0; rr < 3; ++rr) {
            out[i*12+rr*4+0] = gi[rr*4+0];
            out[i*12+rr*4+1] = gi[rr*4+1];
            out[i*12+rr*4+2] = gi[rr*4+2];
            out[i*12+rr*4+3] = gi[rr*4+3] - (gi[rr*4+0]*jx + gi[rr*4+1]*jy + gi[rr*4+2]*jz);
        }
    }
}

// ============ K7: streaming-fragment MFMA GEMM (exact R8 config, 51 us proven) ============
__global__ __launch_bounds__(256, 2) void k_gemm(const short* __restrict__ Af,
        const short* __restrict__ Bf, const float* __restrict__ vt,
        float* __restrict__ vout, int B) {
    __shared__ float eld[64 * 128];                // 32 KB, epilogue transpose only
    const int t = threadIdx.x;
    const int wgid = blockIdx.x;
    const int bt = wgid & 7, nt = wgid >> 3;       // bt per XCD (round-robin dispatch)
    const int wave = t >> 6, lane = t & 63;
    const int wn = (wave & 1) * 64;
    const int q = lane >> 4, r16 = lane & 15;
    const int mfb = (wave >> 1) * 4, nfb = (wave & 1) * 4;

    const s16x8* Ab = (const s16x8*)(Af + (size_t)bt * FTILE);
    const s16x8* Bb = (const s16x8*)(Bf + (size_t)nt * FTILE);

    f32x4 acc[4][4];
    #pragma unroll
    for (int m = 0; m < 4; ++m)
        #pragma unroll
        for (int n = 0; n < 4; ++n)
            #pragma unroll
            for (int i = 0; i < 4; ++i) acc[m][n][i] = 0.0f;

    #pragma unroll
    for (int ks = 0; ks < 8; ++ks) {
        s16x8 a[4], b[4];
        #pragma unroll
        for (int m = 0; m < 4; ++m) a[m] = Ab[(ks*8 + mfb + m)*64 + lane];
        #pragma unroll
        for (int n = 0; n < 4; ++n) b[n] = Bb[(ks*8 + nfb + n)*64 + lane];
        #pragma unroll
        for (int m = 0; m < 4; ++m)
            #pragma unroll
            for (int n = 0; n < 4; ++n)
                acc[m][n] = __builtin_amdgcn_mfma_f32_16x16x32_bf16(a[m], b[n], acc[m][n], 0, 0, 0);
    }

    // ---- epilogue: two 64-row halves through LDS, 512B-contiguous row stores ----
    #pragma unroll
    for (int half = 0; half < 2; ++half) {
        if ((wave >> 1) == half) {
            #pragma unroll
            for (int m = 0; m < 4; ++m) {
                #pragma unroll
                for (int n = 0; n < 4; ++n) {
                    #pragma unroll
                    for (int i = 0; i < 4; ++i) {
                        int row_l = m*16 + q*4 + i;              // 0..63
                        int col = wn + n*16 + r16;               // 0..127
                        eld[row_l * 128 + (col ^ ((row_l & 7) << 2))] = acc[m][n][i];
                    }
                }
            }
        }
        __syncthreads();
        {
            const int c32 = t & 31;
            const int col = c32 * 4;
            const int rsub = (t >> 5) & 1;
            #pragma unroll
            for (int it = 0; it < 8; ++it) {
                int row_l = it * 8 + wave * 2 + rsub;            // 0..63
                int bg = bt * 128 + half * 64 + row_l;
                int rg = nt * 128 + col;
                f32x4 v = *(const f32x4*)&eld[row_l * 128 + (col ^ ((row_l & 7) << 2))];
                if (bg < B) {
                    float* dst = vout + (size_t)bg * NR + rg;
                    if (rg + 3 < NR) {
                        float4 tv = *(const float4*)(vt + rg);
                        v[0] += tv.x; v[1] += tv.y; v[2] += tv.z; v[3] += tv.w;
                        *(f4u*)dst = v;
                    } else {
                        #pragma unroll
                        for (int e = 0; e < 4; ++e)
                            if (rg + e < NR) dst[e] = v[e] + vt[rg + e];
                    }
                }
            }
        }
        __syncthreads();
    }
}

// ============ K8: MFMA skinning (R4-proven), 16 batches/block ============
__global__ __launch_bounds__(256) void k_skin(float* __restrict__ vio,
        const float* __restrict__ W, const float* __restrict__ Gc, int B) {
    __shared__ short Gm[16 * 40];
    const int t = threadIdx.x;
    const int wave = t >> 6, lane = t & 63;
    const int q = lane >> 4, c = lane & 15;
    const int vb = blockIdx.x * 256 + wave * 64;
    const int b0 = blockIdx.y * 16;

    if (t < 320) ((int*)Gm)[t] = 0;

    s16x8 wf[4];
    #pragma unroll
    for (int m = 0; m < 4; ++m) {
        int vert = vb + m*16 + c;
        if (q < 3 && vert < NV) {
            const float* wp = W + (size_t)vert * NJ + q*8;
            float4 f0 = *(const float4*)(wp);
            float4 f1 = *(const float4*)(wp + 4);
            wf[m][0]=f2bf(f0.x); wf[m][1]=f2bf(f0.y); wf[m][2]=f2bf(f0.z); wf[m][3]=f2bf(f0.w);
            wf[m][4]=f2bf(f1.x); wf[m][5]=f2bf(f1.y); wf[m][6]=f2bf(f1.z); wf[m][7]=f2bf(f1.w);
        } else {
            #pragma unroll
            for (int e = 0; e < 8; ++e) wf[m][e] = 0;
        }
    }
    __syncthreads();

    for (int bb = 0; bb < 16; ++bb) {
        int b = b0 + bb;
        if (b >= B) break;
        {
            int i0 = t;
            int j0 = i0 / 12, c0 = i0 - j0*12;
            if (i0 < 288) Gm[c0*40 + j0] = f2bf(Gc[(size_t)b*288 + i0]);
            int i1 = t + 256;
            if (i1 < 288) {
                int j1 = i1 / 12, c1 = i1 - j1*12;
                Gm[c1*40 + j1] = f2bf(Gc[(size_t)b*288 + i1]);
            }
        }
        __syncthreads();

        s16x8 af = *(const s16x8*)&Gm[c*40 + q*8];
        #pragma unroll
        for (int m = 0; m < 4; ++m) {
            f32x4 zz = {0.0f, 0.0f, 0.0f, 0.0f};
            f32x4 acc = __builtin_amdgcn_mfma_f32_16x16x32_bf16(af, wf[m], zz, 0, 0, 0);
            int vert = vb + m*16 + c;
            bool ok = (q < 3) && (vert < NV);
            if (ok) {
                float* vp = vio + (size_t)b * NR + (size_t)vert * 3;
                float x = vp[0], y = vp[1], z = vp[2];
                float o = acc[0]*x + acc[1]*y + acc[2]*z + acc[3];
                vp[q] = o;
            }
        }
        __syncthreads();
    }
}

extern "C" void kernel_launch(void* const* d_in, const int* in_sizes, int n_in,
                              void* d_out, int out_size, void* d_ws, size_t ws_size,
                              hipStream_t stream) {
    const float* theta = (const float*)d_in[0];
    const float* beta  = (const float*)d_in[1];
    const float* sd    = (const float*)d_in[2];
    const float* pd    = (const float*)d_in[3];
    const float* Jreg  = (const float*)d_in[4];
    const float* vt    = (const float*)d_in[5];
    const float* W     = (const float*)d_in[6];
    float* out = (float*)d_out;

    const int B = in_sizes[0] / 72;

    float* vregion = out;
    float* Jout    = out + (size_t)B * NR;

    float* Rws   = (float*)d_ws;                          // B*216 f32
    float* Gcws  = Rws + (size_t)B * 216;                 // B*288 f32
    float* pfA   = Gcws + (size_t)B * 288;                // B*224 f32
    short* Afrag = (short*)(pfA + (size_t)B * 224);       // 8*FTILE bf16 (512 KB)
    short* Bfrag = Afrag + (size_t)(B/128) * FTILE;       // 162*FTILE bf16 (10.4 MB)

    float* part  = vregion;                               // d_out scratch pre-GEMM
    float* part2 = vregion + (size_t)NSPLIT * 72 * 224;
    float* JDt   = part2 + (size_t)8 * 72 * 224;

    k_rodrigues<<<(B*NJ + 255)/256, 256, 0, stream>>>(theta, beta, Rws, pfA, Afrag, B);
    k_convB<<<(NT*8*8*64)/256, 256, 0, stream>>>(pd, sd, Bfrag);
    k_jdirs<<<NSPLIT, 256, 0, stream>>>(pd, sd, vt, Jreg, part);
    {
        dim3 grid(72, 8);
        k_jreduce1<<<grid, 256, 0, stream>>>(part, part2);
    }
    k_jreduce2<<<(72*224 + 255)/256, 256, 0, stream>>>(part2, JDt);
    k_J<<<B, 128, 0, stream>>>(pfA, JDt, Jout, B);
    k_chain<<<(B + 31)/32, 32, 0, stream>>>(Rws, Jout, Gcws, B);
    // streaming-fragment GEMM: 1-D grid, bt = wgid & 7 keeps one A-tile per XCD
    k_gemm<<<NT * (B/128), 256, 0, stream>>>(Afrag, Bfrag, vt, vregion, B);
    {
        dim3 grid((NV + 255)/256, (B + 15)/16);
        k_skin<<<grid, 256, 0, stream>>>(vregion, W, Gcws, B);
    }
}

// Round 13
// 154.016 us; speedup vs baseline: 1.3036x; 1.0025x over previous
//
#include <hip/hip_runtime.h>
#include <hip/hip_bf16.h>

#define NJ 24
#define NV 6890
#define NR (NV*3)        // 20670 output rows per batch
#define NPF 207
#define KB 217           // 207 pf + 10 beta
#define KP 256           // padded K (8 x 32)
#define NT 162           // n-tiles (162*128 = 20736 >= NR)
#define NSPLIT 512       // jdirs v-splits
#define VPB 14           // ceil(6890/512)
#define FTILE 32768      // shorts per fragment tile: 8 ks * 8 frag * 64 lane * 8

typedef short s16x8 __attribute__((ext_vector_type(8)));
typedef short s16x8a __attribute__((ext_vector_type(8), aligned(4)));
typedef float f32x4 __attribute__((ext_vector_type(4)));
typedef float f4u   __attribute__((ext_vector_type(4), aligned(4)));

__device__ constexpr int PAR[24] = {-1,0,0,0,1,2,3,4,5,6,7,8,9,9,9,12,13,14,16,17,18,19,20,21};

__device__ __forceinline__ short f2bf(float f) {
    __hip_bfloat16 h = __float2bfloat16(f);
    return *reinterpret_cast<short*>(&h);
}
__device__ __forceinline__ float bf2f(unsigned short u) {
    unsigned int x = ((unsigned int)u) << 16;
    return __uint_as_float(x);
}

// fragment address for matrix element (row_in_tile, k)
__device__ __forceinline__ size_t frag_addr(int row128, int k) {
    int ks = k >> 5, q = (k >> 3) & 3, e = k & 7;
    int mf = row128 >> 4, r16 = row128 & 15;
    return ((size_t)(ks*8 + mf) * 64 + q*16 + r16) * 8 + e;
}

// ============ K1: Rodrigues -> Rws(f32), pfA(f32), Afrag(bf16 fragment layout) ============
__global__ __launch_bounds__(256) void k_rodrigues(const float* __restrict__ theta,
        const float* __restrict__ beta, float* __restrict__ Rws,
        float* __restrict__ pfA, short* __restrict__ Afrag, int B) {
    int idx = blockIdx.x * blockDim.x + threadIdx.x;   // b*24 + j
    if (idx >= B * NJ) return;
    int b = idx / NJ, j = idx % NJ;
    float x = theta[b*72 + j*3 + 0];
    float y = theta[b*72 + j*3 + 1];
    float z = theta[b*72 + j*3 + 2];
    float n = sqrtf(x*x + y*y + z*z);
    float a = fmaxf(n, 1e-8f);
    float inv = 1.0f / a;
    float ix = x*inv, iy = y*inv, iz = z*inv;
    float c = cosf(a), s = sinf(a), t = 1.0f - c;
    float r[9];
    r[0] = t*ix*ix + c;     r[1] = t*ix*iy - s*iz;  r[2] = t*ix*iz + s*iy;
    r[3] = t*ix*iy + s*iz;  r[4] = t*iy*iy + c;     r[5] = t*iy*iz - s*ix;
    r[6] = t*ix*iz - s*iy;  r[7] = t*iy*iz + s*ix;  r[8] = t*iz*iz + c;
    float* Rp = Rws + (size_t)idx * 9;
    #pragma unroll
    for (int k = 0; k < 9; ++k) Rp[k] = r[k];

    int rb = b & 127;
    short* At = Afrag + (size_t)(b >> 7) * FTILE;
    float* pa = pfA + (size_t)b * 224;
    if (j >= 1) {
        #pragma unroll
        for (int kk = 0; kk < 9; ++kk) {
            int k = (j-1)*9 + kk;
            float f = r[kk] - ((kk == 0 || kk == 4 || kk == 8) ? 1.0f : 0.0f);
            At[frag_addr(rb, k)] = f2bf(f);
            pa[k] = f;
        }
    } else {
        #pragma unroll
        for (int kk = 0; kk < 10; ++kk) {
            int k = NPF + kk;
            float f = beta[b*10 + kk];
            At[frag_addr(rb, k)] = f2bf(f);
            pa[k] = f;
        }
        for (int k = KB; k < KP; ++k)
            At[frag_addr(rb, k)] = 0;
    }
}

// ============ K2: build Bfrag (bf16, fragment layout, coalesced writes) ============
__global__ __launch_bounds__(256) void k_convB(const float* __restrict__ pd,
        const float* __restrict__ sd, short* __restrict__ Bf) {
    int cid = blockIdx.x * 256 + threadIdx.x;      // chunk id: [nt][ks][nf][lane]
    int lane_ = cid & 63;
    int nf = (cid >> 6) & 7;
    int ks = (cid >> 9) & 7;
    int nt = cid >> 12;
    int q = lane_ >> 4, r16 = lane_ & 15;
    int rg = nt*128 + nf*16 + r16;
    int k0 = ks*32 + q*8;
    s16x8 v;
    if (rg < NR) {
        if (k0 + 7 < NPF) {
            const float* p = pd + (size_t)rg * NPF + k0;
            #pragma unroll
            for (int k = 0; k < 8; ++k) v[k] = f2bf(p[k]);
        } else {
            #pragma unroll
            for (int k = 0; k < 8; ++k) {
                int col = k0 + k;
                float f = 0.0f;
                if (col < NPF)     f = pd[(size_t)rg * NPF + col];
                else if (col < KB) f = sd[(size_t)rg * 10 + (col - NPF)];
                v[k] = f2bf(f);
            }
        }
    } else {
        #pragma unroll
        for (int k = 0; k < 8; ++k) v[k] = 0;
    }
    *(s16x8*)&Bf[(size_t)cid * 8] = v;
}

// ============ K3: JD partials, part layout [bi][i(72)][k(224)] ============
__global__ __launch_bounds__(256) void k_jdirs(const float* __restrict__ pd,
        const float* __restrict__ sd, const float* __restrict__ vt,
        const float* __restrict__ Jreg, float* __restrict__ part) {
    __shared__ float wjs[24][VPB];
    int bi = blockIdx.x;
    int v0 = bi * VPB;
    int nv = NV - v0; if (nv > VPB) nv = VPB; if (nv < 0) nv = 0;
    for (int i = threadIdx.x; i < 24*VPB; i += 256) {
        int j = i / VPB, vv = i - j*VPB;
        wjs[j][vv] = (vv < nv) ? Jreg[(size_t)j * NV + v0 + vv] : 0.0f;
    }
    __syncthreads();
    int k = threadIdx.x;
    float acc[72];
    #pragma unroll
    for (int i = 0; i < 72; ++i) acc[i] = 0.0f;
    for (int vv = 0; vv < VPB; ++vv) {
        int v = v0 + vv;
        if (v >= NV) break;
        #pragma unroll
        for (int c = 0; c < 3; ++c) {
            int row = v*3 + c;
            float val = 0.0f;
            if (k < NPF)      val = pd[(size_t)row * NPF + k];
            else if (k < KB)  val = sd[(size_t)row * 10 + (k - NPF)];
            else if (k == KB) val = vt[row];
            #pragma unroll
            for (int j = 0; j < 24; ++j) acc[j*3 + c] += wjs[j][vv] * val;
        }
    }
    if (k < 224) {
        float* p = part + (size_t)bi * (72*224);
        #pragma unroll
        for (int i = 0; i < 72; ++i) p[i*224 + k] = acc[i];
    }
}

// ============ K4a: reduce 512 -> 8 partials, coalesced ============
__global__ __launch_bounds__(256) void k_jreduce1(const float* __restrict__ part,
        float* __restrict__ part2) {
    int i = blockIdx.x;            // 0..71
    int s = blockIdx.y;            // 0..7
    int k = threadIdx.x;
    if (k >= 224) return;
    float acc = 0.0f;
    #pragma unroll 4
    for (int bi = s*64; bi < s*64 + 64; ++bi)
        acc += part[(size_t)bi * (72*224) + i*224 + k];
    part2[((size_t)s * 72 + i) * 224 + k] = acc;
}

// ============ K4b: reduce 8 -> JDt[k][72] ============
__global__ __launch_bounds__(256) void k_jreduce2(const float* __restrict__ part2,
        float* __restrict__ JDt) {
    int e = blockIdx.x * 256 + threadIdx.x;    // e = i*224 + k
    if (e >= 72*224) return;
    int i = e / 224, k = e - i*224;
    float s = 0.0f;
    #pragma unroll
    for (int ss = 0; ss < 8; ++ss)
        s += part2[((size_t)ss * 72 + i) * 224 + k];
    if (k < 218) JDt[k*72 + i] = s;
}

// ============ K5: J[b][jc] = JDt[217][jc] + sum_k pfA[b][k]*JDt[k][jc] ============
__global__ __launch_bounds__(128) void k_J(const float* __restrict__ pfA,
        const float* __restrict__ JDt, float* __restrict__ Jout, int B) {
    int b = blockIdx.x, t = threadIdx.x;
    if (t >= 72) return;
    const float* pa = pfA + (size_t)b * 224;
    float acc = JDt[217*72 + t];
    #pragma unroll 7
    for (int k = 0; k < KB; ++k) acc += pa[k] * JDt[k*72 + t];
    Jout[(size_t)b * 72 + t] = acc;
}

// ============ K6: kinematic chain -> G_corr (B,24,12) ============
__global__ __launch_bounds__(32) void k_chain(const float* __restrict__ Rg,
        const float* __restrict__ Jg, float* __restrict__ Gc, int B) {
    __shared__ float Gs[32 * 289];
    int b = blockIdx.x * 32 + threadIdx.x;
    if (b >= B) return;
    float* G = &Gs[threadIdx.x * 289];
    float Jl[72];
    const float* Jb = Jg + (size_t)b * 72;
    #pragma unroll
    for (int i = 0; i < 72; ++i) Jl[i] = Jb[i];
    const float* Rb = Rg + (size_t)b * 216;
    G[0]=Rb[0]; G[1]=Rb[1]; G[2]=Rb[2];  G[3]=Jl[0];
    G[4]=Rb[3]; G[5]=Rb[4]; G[6]=Rb[5];  G[7]=Jl[1];
    G[8]=Rb[6]; G[9]=Rb[7]; G[10]=Rb[8]; G[11]=Jl[2];
    #pragma unroll
    for (int i = 1; i < NJ; ++i) {
        const int p = PAR[i];
        const float* Ri = Rb + i*9;
        float r00=Ri[0],r01=Ri[1],r02=Ri[2];
        float r10=Ri[3],r11=Ri[4],r12=Ri[5];
        float r20=Ri[6],r21=Ri[7],r22=Ri[8];
        float px=Jl[p*3+0], py=Jl[p*3+1], pz=Jl[p*3+2];
        float tx = Jl[i*3+0] - (r00*px + r01*py + r02*pz);
        float ty = Jl[i*3+1] - (r10*px + r11*py + r12*pz);
        float tz = Jl[i*3+2] - (r20*px + r21*py + r22*pz);
        const float* gp = &G[p*12];
        float* gi = &G[i*12];
        #pragma unroll
        for (int rr = 0; rr < 3; ++rr) {
            float a0=gp[rr*4+0], a1=gp[rr*4+1], a2=gp[rr*4+2], a3=gp[rr*4+3];
            gi[rr*4+0] = a0*r00 + a1*r10 + a2*r20;
            gi[rr*4+1] = a0*r01 + a1*r11 + a2*r21;
            gi[rr*4+2] = a0*r02 + a1*r12 + a2*r22;
            gi[rr*4+3] = a0*tx + a1*ty + a2*tz + a3;
        }
    }
    float* out = Gc + (size_t)b * 288;
    #pragma unroll
    for (int i = 0; i < NJ; ++i) {
        const float* gi = &G[i*12];
        float jx=Jl[i*3+0], jy=Jl[i*3+1], jz=Jl[i*3+2];
        #pragma unroll
        for (int rr = 0; rr < 3; ++rr) {
            out[i*12+rr*4+0] = gi[rr*4+0];
            out[i*12+rr*4+1] = gi[rr*4+1];
            out[i*12+rr*4+2] = gi[rr*4+2];
            out[i*12+rr*4+3] = gi[rr*4+3] - (gi[rr*4+0]*jx + gi[rr*4+1]*jy + gi[rr*4+2]*jz);
        }
    }
}

// ============ K7: streaming-fragment MFMA GEMM, f32 out (exact R8, fallback path) ============
__global__ __launch_bounds__(256, 2) void k_gemm(const short* __restrict__ Af,
        const short* __restrict__ Bf, const float* __restrict__ vt,
        float* __restrict__ vout, int B) {
    __shared__ float eld[64 * 128];
    const int t = threadIdx.x;
    const int wgid = blockIdx.x;
    const int bt = wgid & 7, nt = wgid >> 3;
    const int wave = t >> 6, lane = t & 63;
    const int wn = (wave & 1) * 64;
    const int q = lane >> 4, r16 = lane & 15;
    const int mfb = (wave >> 1) * 4, nfb = (wave & 1) * 4;

    const s16x8* Ab = (const s16x8*)(Af + (size_t)bt * FTILE);
    const s16x8* Bb = (const s16x8*)(Bf + (size_t)nt * FTILE);

    f32x4 acc[4][4];
    #pragma unroll
    for (int m = 0; m < 4; ++m)
        #pragma unroll
        for (int n = 0; n < 4; ++n)
            #pragma unroll
            for (int i = 0; i < 4; ++i) acc[m][n][i] = 0.0f;

    #pragma unroll
    for (int ks = 0; ks < 8; ++ks) {
        s16x8 a[4], b[4];
        #pragma unroll
        for (int m = 0; m < 4; ++m) a[m] = Ab[(ks*8 + mfb + m)*64 + lane];
        #pragma unroll
        for (int n = 0; n < 4; ++n) b[n] = Bb[(ks*8 + nfb + n)*64 + lane];
        #pragma unroll
        for (int m = 0; m < 4; ++m)
            #pragma unroll
            for (int n = 0; n < 4; ++n)
                acc[m][n] = __builtin_amdgcn_mfma_f32_16x16x32_bf16(a[m], b[n], acc[m][n], 0, 0, 0);
    }

    #pragma unroll
    for (int half = 0; half < 2; ++half) {
        if ((wave >> 1) == half) {
            #pragma unroll
            for (int m = 0; m < 4; ++m)
                #pragma unroll
                for (int n = 0; n < 4; ++n)
                    #pragma unroll
                    for (int i = 0; i < 4; ++i) {
                        int row_l = m*16 + q*4 + i;
                        int col = wn + n*16 + r16;
                        eld[row_l * 128 + (col ^ ((row_l & 7) << 2))] = acc[m][n][i];
                    }
        }
        __syncthreads();
        {
            const int c32 = t & 31;
            const int col = c32 * 4;
            const int rsub = (t >> 5) & 1;
            #pragma unroll
            for (int it = 0; it < 8; ++it) {
                int row_l = it * 8 + wave * 2 + rsub;
                int bg = bt * 128 + half * 64 + row_l;
                int rg = nt * 128 + col;
                f32x4 v = *(const f32x4*)&eld[row_l * 128 + (col ^ ((row_l & 7) << 2))];
                if (bg < B) {
                    float* dst = vout + (size_t)bg * NR + rg;
                    if (rg + 3 < NR) {
                        float4 tv = *(const float4*)(vt + rg);
                        v[0] += tv.x; v[1] += tv.y; v[2] += tv.z; v[3] += tv.w;
                        *(f4u*)dst = v;
                    } else {
                        #pragma unroll
                        for (int e = 0; e < 4; ++e)
                            if (rg + e < NR) dst[e] = v[e] + vt[rg + e];
                    }
                }
            }
        }
        __syncthreads();
    }
}

// ============ K7b: same GEMM, bf16 v_posed out to ws ============
__global__ __launch_bounds__(256, 2) void k_gemm_bf(const short* __restrict__ Af,
        const short* __restrict__ Bf, const float* __restrict__ vt,
        short* __restrict__ vpbf, int B) {
    __shared__ float eld[64 * 128];
    const int t = threadIdx.x;
    const int wgid = blockIdx.x;
    const int bt = wgid & 7, nt = wgid >> 3;
    const int wave = t >> 6, lane = t & 63;
    const int wn = (wave & 1) * 64;
    const int q = lane >> 4, r16 = lane & 15;
    const int mfb = (wave >> 1) * 4, nfb = (wave & 1) * 4;

    const s16x8* Ab = (const s16x8*)(Af + (size_t)bt * FTILE);
    const s16x8* Bb = (const s16x8*)(Bf + (size_t)nt * FTILE);

    f32x4 acc[4][4];
    #pragma unroll
    for (int m = 0; m < 4; ++m)
        #pragma unroll
        for (int n = 0; n < 4; ++n)
            #pragma unroll
            for (int i = 0; i < 4; ++i) acc[m][n][i] = 0.0f;

    #pragma unroll
    for (int ks = 0; ks < 8; ++ks) {
        s16x8 a[4], b[4];
        #pragma unroll
        for (int m = 0; m < 4; ++m) a[m] = Ab[(ks*8 + mfb + m)*64 + lane];
        #pragma unroll
        for (int n = 0; n < 4; ++n) b[n] = Bb[(ks*8 + nfb + n)*64 + lane];
        #pragma unroll
        for (int m = 0; m < 4; ++m)
            #pragma unroll
            for (int n = 0; n < 4; ++n)
                acc[m][n] = __builtin_amdgcn_mfma_f32_16x16x32_bf16(a[m], b[n], acc[m][n], 0, 0, 0);
    }

    #pragma unroll
    for (int half = 0; half < 2; ++half) {
        if ((wave >> 1) == half) {
            #pragma unroll
            for (int m = 0; m < 4; ++m)
                #pragma unroll
                for (int n = 0; n < 4; ++n)
                    #pragma unroll
                    for (int i = 0; i < 4; ++i) {
                        int row_l = m*16 + q*4 + i;
                        int col = wn + n*16 + r16;
                        eld[row_l * 128 + (col ^ ((row_l & 7) << 2))] = acc[m][n][i];
                    }
        }
        __syncthreads();
        {
            // 8 bf16 per thread: 16 threads cover one 128-col row (256B), 16 rows/pass
            const int col0 = (t & 15) * 8;
            const int rsub = t >> 4;               // 0..15
            #pragma unroll
            for (int it = 0; it < 4; ++it) {
                int row_l = it * 16 + rsub;        // 0..63
                int bg = bt * 128 + half * 64 + row_l;
                int rg = nt * 128 + col0;
                int sw = (row_l & 7) << 2;
                f32x4 v0 = *(const f32x4*)&eld[row_l * 128 + (col0 ^ sw)];
                f32x4 v1 = *(const f32x4*)&eld[row_l * 128 + ((col0 + 4) ^ sw)];
                if (bg < B) {
                    if (rg + 7 < NR) {
                        float4 t0 = *(const float4*)(vt + rg);
                        float4 t1 = *(const float4*)(vt + rg + 4);
                        s16x8 s;
                        s[0]=f2bf(v0[0]+t0.x); s[1]=f2bf(v0[1]+t0.y);
                        s[2]=f2bf(v0[2]+t0.z); s[3]=f2bf(v0[3]+t0.w);
                        s[4]=f2bf(v1[0]+t1.x); s[5]=f2bf(v1[1]+t1.y);
                        s[6]=f2bf(v1[2]+t1.z); s[7]=f2bf(v1[3]+t1.w);
                        *(s16x8a*)(vpbf + (size_t)bg * NR + rg) = s;
                    } else {
                        #pragma unroll
                        for (int e = 0; e < 8; ++e) {
                            int r = rg + e;
                            if (r < NR) {
                                float f = (e < 4 ? v0[e] : v1[e-4]) + vt[r];
                                vpbf[(size_t)bg * NR + r] = f2bf(f);
                            }
                        }
                    }
                }
            }
        }
        __syncthreads();
    }
}

// ============ K8: MFMA skinning, f32 in-place (fallback) ============
__global__ __launch_bounds__(256) void k_skin(float* __restrict__ vio,
        const float* __restrict__ W, const float* __restrict__ Gc, int B) {
    __shared__ short Gm[16 * 40];
    const int t = threadIdx.x;
    const int wave = t >> 6, lane = t & 63;
    const int q = lane >> 4, c = lane & 15;
    const int vb = blockIdx.x * 256 + wave * 64;
    const int b0 = blockIdx.y * 16;

    if (t < 320) ((int*)Gm)[t] = 0;

    s16x8 wf[4];
    #pragma unroll
    for (int m = 0; m < 4; ++m) {
        int vert = vb + m*16 + c;
        if (q < 3 && vert < NV) {
            const float* wp = W + (size_t)vert * NJ + q*8;
            float4 f0 = *(const float4*)(wp);
            float4 f1 = *(const float4*)(wp + 4);
            wf[m][0]=f2bf(f0.x); wf[m][1]=f2bf(f0.y); wf[m][2]=f2bf(f0.z); wf[m][3]=f2bf(f0.w);
            wf[m][4]=f2bf(f1.x); wf[m][5]=f2bf(f1.y); wf[m][6]=f2bf(f1.z); wf[m][7]=f2bf(f1.w);
        } else {
            #pragma unroll
            for (int e = 0; e < 8; ++e) wf[m][e] = 0;
        }
    }
    __syncthreads();

    for (int bb = 0; bb < 16; ++bb) {
        int b = b0 + bb;
        if (b >= B) break;
        {
            int i0 = t;
            int j0 = i0 / 12, c0 = i0 - j0*12;
            if (i0 < 288) Gm[c0*40 + j0] = f2bf(Gc[(size_t)b*288 + i0]);
            int i1 = t + 256;
            if (i1 < 288) {
                int j1 = i1 / 12, c1 = i1 - j1*12;
                Gm[c1*40 + j1] = f2bf(Gc[(size_t)b*288 + i1]);
            }
        }
        __syncthreads();

        s16x8 af = *(const s16x8*)&Gm[c*40 + q*8];
        #pragma unroll
        for (int m = 0; m < 4; ++m) {
            f32x4 zz = {0.0f, 0.0f, 0.0f, 0.0f};
            f32x4 acc = __builtin_amdgcn_mfma_f32_16x16x32_bf16(af, wf[m], zz, 0, 0, 0);
            int vert = vb + m*16 + c;
            bool ok = (q < 3) && (vert < NV);
            if (ok) {
                float* vp = vio + (size_t)b * NR + (size_t)vert * 3;
                float x = vp[0], y = vp[1], z = vp[2];
                float o = acc[0]*x + acc[1]*y + acc[2]*z + acc[3];
                vp[q] = o;
            }
        }
        __syncthreads();
    }
}

// ============ K8b: MFMA skinning, bf16 v_posed in (ws) -> f32 v_out (d_out) ============
__global__ __launch_bounds__(256) void k_skin_bf(const short* __restrict__ vpbf,
        float* __restrict__ vout,
        const float* __restrict__ W, const float* __restrict__ Gc, int B) {
    __shared__ short Gm[16 * 40];
    const int t = threadIdx.x;
    const int wave = t >> 6, lane = t & 63;
    const int q = lane >> 4, c = lane & 15;
    const int vb = blockIdx.x * 256 + wave * 64;
    const int b0 = blockIdx.y * 16;

    if (t < 320) ((int*)Gm)[t] = 0;

    s16x8 wf[4];
    #pragma unroll
    for (int m = 0; m < 4; ++m) {
        int vert = vb + m*16 + c;
        if (q < 3 && vert < NV) {
            const float* wp = W + (size_t)vert * NJ + q*8;
            float4 f0 = *(const float4*)(wp);
            float4 f1 = *(const float4*)(wp + 4);
            wf[m][0]=f2bf(f0.x); wf[m][1]=f2bf(f0.y); wf[m][2]=f2bf(f0.z); wf[m][3]=f2bf(f0.w);
            wf[m][4]=f2bf(f1.x); wf[m][5]=f2bf(f1.y); wf[m][6]=f2bf(f1.z); wf[m][7]=f2bf(f1.w);
        } else {
            #pragma unroll
            for (int e = 0; e < 8; ++e) wf[m][e] = 0;
        }
    }
    __syncthreads();

    for (int bb = 0; bb < 16; ++bb) {
        int b = b0 + bb;
        if (b >= B) break;
        {
            int i0 = t;
            int j0 = i0 / 12, c0 = i0 - j0*12;
            if (i0 < 288) Gm[c0*40 + j0] = f2bf(Gc[(size_t)b*288 + i0]);
            int i1 = t + 256;
            if (i1 < 288) {
                int j1 = i1 / 12, c1 = i1 - j1*12;
                Gm[c1*40 + j1] = f2bf(Gc[(size_t)b*288 + i1]);
            }
        }
        __syncthreads();

        s16x8 af = *(const s16x8*)&Gm[c*40 + q*8];
        #pragma unroll
        for (int m = 0; m < 4; ++m) {
            f32x4 zz = {0.0f, 0.0f, 0.0f, 0.0f};
            f32x4 acc = __builtin_amdgcn_mfma_f32_16x16x32_bf16(af, wf[m], zz, 0, 0, 0);
            int vert = vb + m*16 + c;
            bool ok = (q < 3) && (vert < NV);
            if (ok) {
                const unsigned short* vp = (const unsigned short*)(vpbf + (size_t)b * NR + (size_t)vert * 3);
                float x = bf2f(vp[0]), y = bf2f(vp[1]), z = bf2f(vp[2]);
                float o = acc[0]*x + acc[1]*y + acc[2]*z + acc[3];
                vout[(size_t)b * NR + (size_t)vert * 3 + q] = o;
            }
        }
        __syncthreads();
    }
}

extern "C" void kernel_launch(void* const* d_in, const int* in_sizes, int n_in,
                              void* d_out, int out_size, void* d_ws, size_t ws_size,
                              hipStream_t stream) {
    const float* theta = (const float*)d_in[0];
    const float* beta  = (const float*)d_in[1];
    const float* sd    = (const float*)d_in[2];
    const float* pd    = (const float*)d_in[3];
    const float* Jreg  = (const float*)d_in[4];
    const float* vt    = (const float*)d_in[5];
    const float* W     = (const float*)d_in[6];
    float* out = (float*)d_out;

    const int B = in_sizes[0] / 72;

    float* vregion = out;
    float* Jout    = out + (size_t)B * NR;

    float* Rws   = (float*)d_ws;                          // B*216 f32
    float* Gcws  = Rws + (size_t)B * 216;                 // B*288 f32
    float* pfA   = Gcws + (size_t)B * 288;                // B*224 f32
    short* Afrag = (short*)(pfA + (size_t)B * 224);       // 8*FTILE bf16 (512 KB)
    short* Bfrag = Afrag + (size_t)(B/128) * FTILE;       // 162*FTILE bf16 (10.6 MB)
    short* vpbf  = Bfrag + (size_t)NT * FTILE;            // B*NR bf16 (42.3 MB, optional)

    size_t base_bytes = (size_t)B * 2912 + (size_t)(B/128) * FTILE * 2 + (size_t)NT * FTILE * 2;
    size_t need_bf    = base_bytes + (size_t)B * NR * 2;
    const bool use_bf = (ws_size >= need_bf);

    float* part  = vregion;                               // d_out scratch pre-GEMM
    float* part2 = vregion + (size_t)NSPLIT * 72 * 224;
    float* JDt   = part2 + (size_t)8 * 72 * 224;

    k_rodrigues<<<(B*NJ + 255)/256, 256, 0, stream>>>(theta, beta, Rws, pfA, Afrag, B);
    k_convB<<<(NT*8*8*64)/256, 256, 0, stream>>>(pd, sd, Bfrag);
    k_jdirs<<<NSPLIT, 256, 0, stream>>>(pd, sd, vt, Jreg, part);
    {
        dim3 grid(72, 8);
        k_jreduce1<<<grid, 256, 0, stream>>>(part, part2);
    }
    k_jreduce2<<<(72*224 + 255)/256, 256, 0, stream>>>(part2, JDt);
    k_J<<<B, 128, 0, stream>>>(pfA, JDt, Jout, B);
    k_chain<<<(B + 31)/32, 32, 0, stream>>>(Rws, Jout, Gcws, B);

    if (use_bf) {
        k_gemm_bf<<<NT * (B/128), 256, 0, stream>>>(Afrag, Bfrag, vt, vpbf, B);
        dim3 grid((NV + 255)/256, (B + 15)/16);
        k_skin_bf<<<grid, 256, 0, stream>>>(vpbf, vregion, W, Gcws, B);
    } else {
        k_gemm<<<NT * (B/128), 256, 0, stream>>>(Afrag, Bfrag, vt, vregion, B);
        dim3 grid((NV + 255)/256, (B + 15)/16);
        k_skin<<<grid, 256, 0, stream>>>(vregion, W, Gcws, B);
    }
}

// Round 14
// 153.382 us; speedup vs baseline: 1.3090x; 1.0041x over previous
//
#include <hip/hip_runtime.h>
#include <hip/hip_bf16.h>

#define NJ 24
#define NV 6890
#define NR (NV*3)        // 20670 output rows per batch
#define NPF 207
#define KB 217           // 207 pf + 10 beta
#define KP 256           // padded K (8 x 32)
#define NT 162           // n-tiles (162*128 = 20736 >= NR)
#define NSPLIT 512      // jdirs v-splits
#define VPB 14           // ceil(6890/512)
#define FTILE 32768      // shorts per fragment tile: 8 ks * 8 frag * 64 lane * 8

typedef short s16x8 __attribute__((ext_vector_type(8)));
typedef short s16x8a __attribute__((ext_vector_type(8), aligned(4)));
typedef float f32x4 __attribute__((ext_vector_type(4)));
typedef float f4u   __attribute__((ext_vector_type(4), aligned(4)));

__device__ constexpr int PAR[24] = {-1,0,0,0,1,2,3,4,5,6,7,8,9,9,9,12,13,14,16,17,18,19,20,21};

__device__ __forceinline__ short f2bf(float f) {
    __hip_bfloat16 h = __float2bfloat16(f);
    return *reinterpret_cast<short*>(&h);
}
__device__ __forceinline__ float bf2f(unsigned short u) {
    unsigned int x = ((unsigned int)u) << 16;
    return __uint_as_float(x);
}

// fragment address for matrix element (row_in_tile, k)
__device__ __forceinline__ size_t frag_addr(int row128, int k) {
    int ks = k >> 5, q = (k >> 3) & 3, e = k & 7;
    int mf = row128 >> 4, r16 = row128 & 15;
    return ((size_t)(ks*8 + mf) * 64 + q*16 + r16) * 8 + e;
}

// ============ K1: Rodrigues -> Rws(f32), pfA(f32), Afrag(bf16 fragment layout) ============
__global__ __launch_bounds__(256) void k_rodrigues(const float* __restrict__ theta,
        const float* __restrict__ beta, float* __restrict__ Rws,
        float* __restrict__ pfA, short* __restrict__ Afrag, int B) {
    int idx = blockIdx.x * blockDim.x + threadIdx.x;   // b*24 + j
    if (idx >= B * NJ) return;
    int b = idx / NJ, j = idx % NJ;
    float x = theta[b*72 + j*3 + 0];
    float y = theta[b*72 + j*3 + 1];
    float z = theta[b*72 + j*3 + 2];
    float n = sqrtf(x*x + y*y + z*z);
    float a = fmaxf(n, 1e-8f);
    float inv = 1.0f / a;
    float ix = x*inv, iy = y*inv, iz = z*inv;
    float c = cosf(a), s = sinf(a), t = 1.0f - c;
    float r[9];
    r[0] = t*ix*ix + c;     r[1] = t*ix*iy - s*iz;  r[2] = t*ix*iz + s*iy;
    r[3] = t*ix*iy + s*iz;  r[4] = t*iy*iy + c;     r[5] = t*iy*iz - s*ix;
    r[6] = t*ix*iz - s*iy;  r[7] = t*iy*iz + s*ix;  r[8] = t*iz*iz + c;
    float* Rp = Rws + (size_t)idx * 9;
    #pragma unroll
    for (int k = 0; k < 9; ++k) Rp[k] = r[k];

    int rb = b & 127;
    short* At = Afrag + (size_t)(b >> 7) * FTILE;
    float* pa = pfA + (size_t)b * 224;
    if (j >= 1) {
        #pragma unroll
        for (int kk = 0; kk < 9; ++kk) {
            int k = (j-1)*9 + kk;
            float f = r[kk] - ((kk == 0 || kk == 4 || kk == 8) ? 1.0f : 0.0f);
            At[frag_addr(rb, k)] = f2bf(f);
            pa[k] = f;
        }
    } else {
        #pragma unroll
        for (int kk = 0; kk < 10; ++kk) {
            int k = NPF + kk;
            float f = beta[b*10 + kk];
            At[frag_addr(rb, k)] = f2bf(f);
            pa[k] = f;
        }
        for (int k = KB; k < KP; ++k)
            At[frag_addr(rb, k)] = 0;
    }
}

// ============ K2: build Bfrag (bf16, fragment layout, coalesced writes) ============
__global__ __launch_bounds__(256) void k_convB(const float* __restrict__ pd,
        const float* __restrict__ sd, short* __restrict__ Bf) {
    int cid = blockIdx.x * 256 + threadIdx.x;      // chunk id: [nt][ks][nf][lane]
    int lane_ = cid & 63;
    int nf = (cid >> 6) & 7;
    int ks = (cid >> 9) & 7;
    int nt = cid >> 12;
    int q = lane_ >> 4, r16 = lane_ & 15;
    int rg = nt*128 + nf*16 + r16;
    int k0 = ks*32 + q*8;
    s16x8 v;
    if (rg < NR) {
        if (k0 + 7 < NPF) {
            const float* p = pd + (size_t)rg * NPF + k0;
            #pragma unroll
            for (int k = 0; k < 8; ++k) v[k] = f2bf(p[k]);
        } else {
            #pragma unroll
            for (int k = 0; k < 8; ++k) {
                int col = k0 + k;
                float f = 0.0f;
                if (col < NPF)     f = pd[(size_t)rg * NPF + col];
                else if (col < KB) f = sd[(size_t)rg * 10 + (col - NPF)];
                v[k] = f2bf(f);
            }
        }
    } else {
        #pragma unroll
        for (int k = 0; k < 8; ++k) v[k] = 0;
    }
    *(s16x8*)&Bf[(size_t)cid * 8] = v;
}

// ============ K3: JD partials, part layout [bi][i(72)][k(224)] ============
__global__ __launch_bounds__(256) void k_jdirs(const float* __restrict__ pd,
        const float* __restrict__ sd, const float* __restrict__ vt,
        const float* __restrict__ Jreg, float* __restrict__ part) {
    __shared__ float wjs[24][VPB];
    int bi = blockIdx.x;
    int v0 = bi * VPB;
    int nv = NV - v0; if (nv > VPB) nv = VPB; if (nv < 0) nv = 0;
    for (int i = threadIdx.x; i < 24*VPB; i += 256) {
        int j = i / VPB, vv = i - j*VPB;
        wjs[j][vv] = (vv < nv) ? Jreg[(size_t)j * NV + v0 + vv] : 0.0f;
    }
    __syncthreads();
    int k = threadIdx.x;
    float acc[72];
    #pragma unroll
    for (int i = 0; i < 72; ++i) acc[i] = 0.0f;
    for (int vv = 0; vv < VPB; ++vv) {
        int v = v0 + vv;
        if (v >= NV) break;
        #pragma unroll
        for (int c = 0; c < 3; ++c) {
            int row = v*3 + c;
            float val = 0.0f;
            if (k < NPF)      val = pd[(size_t)row * NPF + k];
            else if (k < KB)  val = sd[(size_t)row * 10 + (k - NPF)];
            else if (k == KB) val = vt[row];
            #pragma unroll
            for (int j = 0; j < 24; ++j) acc[j*3 + c] += wjs[j][vv] * val;
        }
    }
    if (k < 224) {
        float* p = part + (size_t)bi * (72*224);
        #pragma unroll
        for (int i = 0; i < 72; ++i) p[i*224 + k] = acc[i];
    }
}

// ============ K4a: reduce 512 -> 8 partials, coalesced ============
__global__ __launch_bounds__(256) void k_jreduce1(const float* __restrict__ part,
        float* __restrict__ part2) {
    int i = blockIdx.x;            // 0..71
    int s = blockIdx.y;            // 0..7
    int k = threadIdx.x;
    if (k >= 224) return;
    float acc = 0.0f;
    #pragma unroll 4
    for (int bi = s*64; bi < s*64 + 64; ++bi)
        acc += part[(size_t)bi * (72*224) + i*224 + k];
    part2[((size_t)s * 72 + i) * 224 + k] = acc;
}

// ============ K4b: reduce 8 -> JDt[k][72] ============
__global__ __launch_bounds__(256) void k_jreduce2(const float* __restrict__ part2,
        float* __restrict__ JDt) {
    int e = blockIdx.x * 256 + threadIdx.x;    // e = i*224 + k
    if (e >= 72*224) return;
    int i = e / 224, k = e - i*224;
    float s = 0.0f;
    #pragma unroll
    for (int ss = 0; ss < 8; ++ss)
        s += part2[((size_t)ss * 72 + i) * 224 + k];
    if (k < 218) JDt[k*72 + i] = s;
}

// ============ K5: J[b][jc] = JDt[217][jc] + sum_k pfA[b][k]*JDt[k][jc] ============
__global__ __launch_bounds__(128) void k_J(const float* __restrict__ pfA,
        const float* __restrict__ JDt, float* __restrict__ Jout, int B) {
    int b = blockIdx.x, t = threadIdx.x;
    if (t >= 72) return;
    const float* pa = pfA + (size_t)b * 224;
    float acc = JDt[217*72 + t];
    #pragma unroll 7
    for (int k = 0; k < KB; ++k) acc += pa[k] * JDt[k*72 + t];
    Jout[(size_t)b * 72 + t] = acc;
}

// ============ K6: kinematic chain -> G_corr (B,24,12) ============
__global__ __launch_bounds__(32) void k_chain(const float* __restrict__ Rg,
        const float* __restrict__ Jg, float* __restrict__ Gc, int B) {
    __shared__ float Gs[32 * 289];
    int b = blockIdx.x * 32 + threadIdx.x;
    if (b >= B) return;
    float* G = &Gs[threadIdx.x * 289];
    float Jl[72];
    const float* Jb = Jg + (size_t)b * 72;
    #pragma unroll
    for (int i = 0; i < 72; ++i) Jl[i] = Jb[i];
    const float* Rb = Rg + (size_t)b * 216;
    G[0]=Rb[0]; G[1]=Rb[1]; G[2]=Rb[2];  G[3]=Jl[0];
    G[4]=Rb[3]; G[5]=Rb[4]; G[6]=Rb[5];  G[7]=Jl[1];
    G[8]=Rb[6]; G[9]=Rb[7]; G[10]=Rb[8]; G[11]=Jl[2];
    #pragma unroll
    for (int i = 1; i < NJ; ++i) {
        const int p = PAR[i];
        const float* Ri = Rb + i*9;
        float r00=Ri[0],r01=Ri[1],r02=Ri[2];
        float r10=Ri[3],r11=Ri[4],r12=Ri[5];
        float r20=Ri[6],r21=Ri[7],r22=Ri[8];
        float px=Jl[p*3+0], py=Jl[p*3+1], pz=Jl[p*3+2];
        float tx = Jl[i*3+0] - (r00*px + r01*py + r02*pz);
        float ty = Jl[i*3+1] - (r10*px + r11*py + r12*pz);
        float tz = Jl[i*3+2] - (r20*px + r21*py + r22*pz);
        const float* gp = &G[p*12];
        float* gi = &G[i*12];
        #pragma unroll
        for (int rr = 0; rr < 3; ++rr) {
            float a0=gp[rr*4+0], a1=gp[rr*4+1], a2=gp[rr*4+2], a3=gp[rr*4+3];
            gi[rr*4+0] = a0*r00 + a1*r10 + a2*r20;
            gi[rr*4+1] = a0*r01 + a1*r11 + a2*r21;
            gi[rr*4+2] = a0*r02 + a1*r12 + a2*r22;
            gi[rr*4+3] = a0*tx + a1*ty + a2*tz + a3;
        }
    }
    float* out = Gc + (size_t)b * 288;
    #pragma unroll
    for (int i = 0; i < NJ; ++i) {
        const float* gi = &G[i*12];
        float jx=Jl[i*3+0], jy=Jl[i*3+1], jz=Jl[i*3+2];
        #pragma unroll
        for (int rr = 0; rr < 3; ++rr) {
            out[i*12+rr*4+0] = gi[rr*4+0];
            out[i*12+rr*4+1] = gi[rr*4+1];
            out[i*12+rr*4+2] = gi[rr*4+2];
            out[i*12+rr*4+3] = gi[rr*4+3] - (gi[rr*4+0]*jx + gi[rr*4+1]*jy + gi[rr*4+2]*jz);
        }
    }
}

// ============ K6b: Gmf[b][lane][8] bf16 skin-A-fragments from G_corr (R9-proven layout) ============
__global__ __launch_bounds__(256) void k_gmf(const float* __restrict__ Gc,
        short* __restrict__ Gmf, int B) {
    int idx = blockIdx.x * 256 + threadIdx.x;      // b*64 + lane
    if (idx >= B * 64) return;
    int lane_ = idx & 63, b = idx >> 6;
    int q = lane_ >> 4, c = lane_ & 15;
    s16x8 v;
    if (c < 12 && q < 3) {
        #pragma unroll
        for (int e = 0; e < 8; ++e)
            v[e] = f2bf(Gc[(size_t)b * 288 + (q*8 + e)*12 + c]);
    } else {
        #pragma unroll
        for (int e = 0; e < 8; ++e) v[e] = 0;
    }
    *(s16x8*)&Gmf[(size_t)idx * 8] = v;
}

// ============ K7: streaming-fragment MFMA GEMM, f32 out (fallback path) ============
__global__ __launch_bounds__(256, 2) void k_gemm(const short* __restrict__ Af,
        const short* __restrict__ Bf, const float* __restrict__ vt,
        float* __restrict__ vout, int B) {
    __shared__ float eld[64 * 128];
    const int t = threadIdx.x;
    const int wgid = blockIdx.x;
    const int bt = wgid & 7, nt = wgid >> 3;
    const int wave = t >> 6, lane = t & 63;
    const int wn = (wave & 1) * 64;
    const int q = lane >> 4, r16 = lane & 15;
    const int mfb = (wave >> 1) * 4, nfb = (wave & 1) * 4;

    const s16x8* Ab = (const s16x8*)(Af + (size_t)bt * FTILE);
    const s16x8* Bb = (const s16x8*)(Bf + (size_t)nt * FTILE);

    f32x4 acc[4][4];
    #pragma unroll
    for (int m = 0; m < 4; ++m)
        #pragma unroll
        for (int n = 0; n < 4; ++n)
            #pragma unroll
            for (int i = 0; i < 4; ++i) acc[m][n][i] = 0.0f;

    #pragma unroll
    for (int ks = 0; ks < 8; ++ks) {
        s16x8 a[4], b[4];
        #pragma unroll
        for (int m = 0; m < 4; ++m) a[m] = Ab[(ks*8 + mfb + m)*64 + lane];
        #pragma unroll
        for (int n = 0; n < 4; ++n) b[n] = Bb[(ks*8 + nfb + n)*64 + lane];
        #pragma unroll
        for (int m = 0; m < 4; ++m)
            #pragma unroll
            for (int n = 0; n < 4; ++n)
                acc[m][n] = __builtin_amdgcn_mfma_f32_16x16x32_bf16(a[m], b[n], acc[m][n], 0, 0, 0);
    }

    #pragma unroll
    for (int half = 0; half < 2; ++half) {
        if ((wave >> 1) == half) {
            #pragma unroll
            for (int m = 0; m < 4; ++m)
                #pragma unroll
                for (int n = 0; n < 4; ++n)
                    #pragma unroll
                    for (int i = 0; i < 4; ++i) {
                        int row_l = m*16 + q*4 + i;
                        int col = wn + n*16 + r16;
                        eld[row_l * 128 + (col ^ ((row_l & 7) << 2))] = acc[m][n][i];
                    }
        }
        __syncthreads();
        {
            const int c32 = t & 31;
            const int col = c32 * 4;
            const int rsub = (t >> 5) & 1;
            #pragma unroll
            for (int it = 0; it < 8; ++it) {
                int row_l = it * 8 + wave * 2 + rsub;
                int bg = bt * 128 + half * 64 + row_l;
                int rg = nt * 128 + col;
                f32x4 v = *(const f32x4*)&eld[row_l * 128 + (col ^ ((row_l & 7) << 2))];
                if (bg < B) {
                    float* dst = vout + (size_t)bg * NR + rg;
                    if (rg + 3 < NR) {
                        float4 tv = *(const float4*)(vt + rg);
                        v[0] += tv.x; v[1] += tv.y; v[2] += tv.z; v[3] += tv.w;
                        *(f4u*)dst = v;
                    } else {
                        #pragma unroll
                        for (int e = 0; e < 4; ++e)
                            if (rg + e < NR) dst[e] = v[e] + vt[rg + e];
                    }
                }
            }
        }
        __syncthreads();
    }
}

// ============ K7b: same GEMM, bf16 v_posed out to ws ============
__global__ __launch_bounds__(256, 2) void k_gemm_bf(const short* __restrict__ Af,
        const short* __restrict__ Bf, const float* __restrict__ vt,
        short* __restrict__ vpbf, int B) {
    __shared__ float eld[64 * 128];
    const int t = threadIdx.x;
    const int wgid = blockIdx.x;
    const int bt = wgid & 7, nt = wgid >> 3;
    const int wave = t >> 6, lane = t & 63;
    const int wn = (wave & 1) * 64;
    const int q = lane >> 4, r16 = lane & 15;
    const int mfb = (wave >> 1) * 4, nfb = (wave & 1) * 4;

    const s16x8* Ab = (const s16x8*)(Af + (size_t)bt * FTILE);
    const s16x8* Bb = (const s16x8*)(Bf + (size_t)nt * FTILE);

    f32x4 acc[4][4];
    #pragma unroll
    for (int m = 0; m < 4; ++m)
        #pragma unroll
        for (int n = 0; n < 4; ++n)
            #pragma unroll
            for (int i = 0; i < 4; ++i) acc[m][n][i] = 0.0f;

    #pragma unroll
    for (int ks = 0; ks < 8; ++ks) {
        s16x8 a[4], b[4];
        #pragma unroll
        for (int m = 0; m < 4; ++m) a[m] = Ab[(ks*8 + mfb + m)*64 + lane];
        #pragma unroll
        for (int n = 0; n < 4; ++n) b[n] = Bb[(ks*8 + nfb + n)*64 + lane];
        #pragma unroll
        for (int m = 0; m < 4; ++m)
            #pragma unroll
            for (int n = 0; n < 4; ++n)
                acc[m][n] = __builtin_amdgcn_mfma_f32_16x16x32_bf16(a[m], b[n], acc[m][n], 0, 0, 0);
    }

    #pragma unroll
    for (int half = 0; half < 2; ++half) {
        if ((wave >> 1) == half) {
            #pragma unroll
            for (int m = 0; m < 4; ++m)
                #pragma unroll
                for (int n = 0; n < 4; ++n)
                    #pragma unroll
                    for (int i = 0; i < 4; ++i) {
                        int row_l = m*16 + q*4 + i;
                        int col = wn + n*16 + r16;
                        eld[row_l * 128 + (col ^ ((row_l & 7) << 2))] = acc[m][n][i];
                    }
        }
        __syncthreads();
        {
            const int col0 = (t & 15) * 8;
            const int rsub = t >> 4;               // 0..15
            #pragma unroll
            for (int it = 0; it < 4; ++it) {
                int row_l = it * 16 + rsub;        // 0..63
                int bg = bt * 128 + half * 64 + row_l;
                int rg = nt * 128 + col0;
                int sw = (row_l & 7) << 2;
                f32x4 v0 = *(const f32x4*)&eld[row_l * 128 + (col0 ^ sw)];
                f32x4 v1 = *(const f32x4*)&eld[row_l * 128 + ((col0 + 4) ^ sw)];
                if (bg < B) {
                    if (rg + 7 < NR) {
                        float4 t0 = *(const float4*)(vt + rg);
                        float4 t1 = *(const float4*)(vt + rg + 4);
                        s16x8 s;
                        s[0]=f2bf(v0[0]+t0.x); s[1]=f2bf(v0[1]+t0.y);
                        s[2]=f2bf(v0[2]+t0.z); s[3]=f2bf(v0[3]+t0.w);
                        s[4]=f2bf(v1[0]+t1.x); s[5]=f2bf(v1[1]+t1.y);
                        s[6]=f2bf(v1[2]+t1.z); s[7]=f2bf(v1[3]+t1.w);
                        *(s16x8a*)(vpbf + (size_t)bg * NR + rg) = s;
                    } else {
                        #pragma unroll
                        for (int e = 0; e < 8; ++e) {
                            int r = rg + e;
                            if (r < NR) {
                                float f = (e < 4 ? v0[e] : v1[e-4]) + vt[r];
                                vpbf[(size_t)bg * NR + r] = f2bf(f);
                            }
                        }
                    }
                }
            }
        }
        __syncthreads();
    }
}

// ============ K8: MFMA skinning, f32 in-place (fallback) ============
__global__ __launch_bounds__(256) void k_skin(float* __restrict__ vio,
        const float* __restrict__ W, const float* __restrict__ Gc, int B) {
    __shared__ short Gm[16 * 40];
    const int t = threadIdx.x;
    const int wave = t >> 6, lane = t & 63;
    const int q = lane >> 4, c = lane & 15;
    const int vb = blockIdx.x * 256 + wave * 64;
    const int b0 = blockIdx.y * 16;

    if (t < 320) ((int*)Gm)[t] = 0;

    s16x8 wf[4];
    #pragma unroll
    for (int m = 0; m < 4; ++m) {
        int vert = vb + m*16 + c;
        if (q < 3 && vert < NV) {
            const float* wp = W + (size_t)vert * NJ + q*8;
            float4 f0 = *(const float4*)(wp);
            float4 f1 = *(const float4*)(wp + 4);
            wf[m][0]=f2bf(f0.x); wf[m][1]=f2bf(f0.y); wf[m][2]=f2bf(f0.z); wf[m][3]=f2bf(f0.w);
            wf[m][4]=f2bf(f1.x); wf[m][5]=f2bf(f1.y); wf[m][6]=f2bf(f1.z); wf[m][7]=f2bf(f1.w);
        } else {
            #pragma unroll
            for (int e = 0; e < 8; ++e) wf[m][e] = 0;
        }
    }
    __syncthreads();

    for (int bb = 0; bb < 16; ++bb) {
        int b = b0 + bb;
        if (b >= B) break;
        {
            int i0 = t;
            int j0 = i0 / 12, c0 = i0 - j0*12;
            if (i0 < 288) Gm[c0*40 + j0] = f2bf(Gc[(size_t)b*288 + i0]);
            int i1 = t + 256;
            if (i1 < 288) {
                int j1 = i1 / 12, c1 = i1 - j1*12;
                Gm[c1*40 + j1] = f2bf(Gc[(size_t)b*288 + i1]);
            }
        }
        __syncthreads();

        s16x8 af = *(const s16x8*)&Gm[c*40 + q*8];
        #pragma unroll
        for (int m = 0; m < 4; ++m) {
            f32x4 zz = {0.0f, 0.0f, 0.0f, 0.0f};
            f32x4 acc = __builtin_amdgcn_mfma_f32_16x16x32_bf16(af, wf[m], zz, 0, 0, 0);
            int vert = vb + m*16 + c;
            bool ok = (q < 3) && (vert < NV);
            if (ok) {
                float* vp = vio + (size_t)b * NR + (size_t)vert * 3;
                float x = vp[0], y = vp[1], z = vp[2];
                float o = acc[0]*x + acc[1]*y + acc[2]*z + acc[3];
                vp[q] = o;
            }
        }
        __syncthreads();
    }
}

// ============ K8b: barrier-free MFMA skinning: Gmf fragments + bf16 in -> f32 out ============
__global__ __launch_bounds__(256) void k_skin_bf(const short* __restrict__ vpbf,
        float* __restrict__ vout, const float* __restrict__ W,
        const short* __restrict__ Gmf, int B) {
    const int t = threadIdx.x;
    const int wave = t >> 6, lane = t & 63;
    const int q = lane >> 4, c = lane & 15;
    const int vb = blockIdx.x * 256 + wave * 64;
    const int b0 = blockIdx.y * 16;

    // W fragments once per block (reused over 16 batches)
    s16x8 wf[4];
    #pragma unroll
    for (int m = 0; m < 4; ++m) {
        int vert = vb + m*16 + c;
        if (q < 3 && vert < NV) {
            const float* wp = W + (size_t)vert * NJ + q*8;
            float4 f0 = *(const float4*)(wp);
            float4 f1 = *(const float4*)(wp + 4);
            wf[m][0]=f2bf(f0.x); wf[m][1]=f2bf(f0.y); wf[m][2]=f2bf(f0.z); wf[m][3]=f2bf(f0.w);
            wf[m][4]=f2bf(f1.x); wf[m][5]=f2bf(f1.y); wf[m][6]=f2bf(f1.z); wf[m][7]=f2bf(f1.w);
        } else {
            #pragma unroll
            for (int e = 0; e < 8; ++e) wf[m][e] = 0;
        }
    }

    #pragma unroll 4
    for (int bb = 0; bb < 16; ++bb) {
        int b = b0 + bb;
        if (b >= B) break;
        s16x8 af = *(const s16x8*)&Gmf[((size_t)b * 64 + lane) * 8];
        #pragma unroll
        for (int m = 0; m < 4; ++m) {
            f32x4 zz = {0.0f, 0.0f, 0.0f, 0.0f};
            f32x4 acc = __builtin_amdgcn_mfma_f32_16x16x32_bf16(af, wf[m], zz, 0, 0, 0);
            int vert = vb + m*16 + c;
            bool ok = (q < 3) && (vert < NV);
            if (ok) {
                const unsigned short* vp = (const unsigned short*)(vpbf + (size_t)b * NR + (size_t)vert * 3);
                float x = bf2f(vp[0]), y = bf2f(vp[1]), z = bf2f(vp[2]);
                float o = acc[0]*x + acc[1]*y + acc[2]*z + acc[3];
                vout[(size_t)b * NR + (size_t)vert * 3 + q] = o;
            }
        }
    }
}

extern "C" void kernel_launch(void* const* d_in, const int* in_sizes, int n_in,
                              void* d_out, int out_size, void* d_ws, size_t ws_size,
                              hipStream_t stream) {
    const float* theta = (const float*)d_in[0];
    const float* beta  = (const float*)d_in[1];
    const float* sd    = (const float*)d_in[2];
    const float* pd    = (const float*)d_in[3];
    const float* Jreg  = (const float*)d_in[4];
    const float* vt    = (const float*)d_in[5];
    const float* W     = (const float*)d_in[6];
    float* out = (float*)d_out;

    const int B = in_sizes[0] / 72;

    float* vregion = out;
    float* Jout    = out + (size_t)B * NR;

    float* Rws   = (float*)d_ws;                          // B*216 f32
    float* Gcws  = Rws + (size_t)B * 216;                 // B*288 f32
    float* pfA   = Gcws + (size_t)B * 288;                // B*224 f32
    short* Afrag = (short*)(pfA + (size_t)B * 224);       // 8*FTILE bf16 (512 KB)
    short* Bfrag = Afrag + (size_t)(B/128) * FTILE;       // 162*FTILE bf16 (10.6 MB)
    short* vpbf  = Bfrag + (size_t)NT * FTILE;            // B*NR bf16 (42.3 MB, optional)
    short* Gmf   = vpbf + (size_t)B * NR;                 // B*512 bf16 (1 MB, optional)

    size_t base_bytes = (size_t)B * 2912 + (size_t)(B/128) * FTILE * 2 + (size_t)NT * FTILE * 2;
    size_t need_bf    = base_bytes + (size_t)B * NR * 2 + (size_t)B * 512 * 2;
    const bool use_bf = (ws_size >= need_bf);

    float* part  = vregion;                               // d_out scratch pre-GEMM
    float* part2 = vregion + (size_t)NSPLIT * 72 * 224;
    float* JDt   = part2 + (size_t)8 * 72 * 224;

    k_rodrigues<<<(B*NJ + 255)/256, 256, 0, stream>>>(theta, beta, Rws, pfA, Afrag, B);
    k_convB<<<(NT*8*8*64)/256, 256, 0, stream>>>(pd, sd, Bfrag);
    k_jdirs<<<NSPLIT, 256, 0, stream>>>(pd, sd, vt, Jreg, part);
    {
        dim3 grid(72, 8);
        k_jreduce1<<<grid, 256, 0, stream>>>(part, part2);
    }
    k_jreduce2<<<(72*224 + 255)/256, 256, 0, stream>>>(part2, JDt);
    k_J<<<B, 128, 0, stream>>>(pfA, JDt, Jout, B);
    k_chain<<<(B + 31)/32, 32, 0, stream>>>(Rws, Jout, Gcws, B);

    if (use_bf) {
        k_gmf<<<(B*64 + 255)/256, 256, 0, stream>>>(Gcws, Gmf, B);
        k_gemm_bf<<<NT * (B/128), 256, 0, stream>>>(Afrag, Bfrag, vt, vpbf, B);
        dim3 grid((NV + 255)/256, (B + 15)/16);
        k_skin_bf<<<grid, 256, 0, stream>>>(vpbf, vregion, W, Gmf, B);
    } else {
        k_gemm<<<NT * (B/128), 256, 0, stream>>>(Afrag, Bfrag, vt, vregion, B);
        dim3 grid((NV + 255)/256, (B + 15)/16);
        k_skin<<<grid, 256, 0, stream>>>(vregion, W, Gcws, B);
    }
}